// Round 9
// baseline (54.601 us; speedup 1.0000x reference)
//
#include <hip/hip_runtime.h>
#include <float.h>
#include <math.h>

typedef __attribute__((ext_vector_type(8))) short short8;
typedef __attribute__((ext_vector_type(8))) _Float16 half8;
typedef __attribute__((ext_vector_type(4))) float f32x4;

constexpr int B_N  = 8192;
constexpr int D_KK = 128;
constexpr int NCLS = 50;
constexpr int NCHUNK = 16;             // 512 cols per chunk
constexpr int CCOLS = B_N / NCHUNK;    // 512
constexpr int NPBLK = 32;
constexpr float C_SCALE = 28.853900817779268f;   // 20*log2(e), folded into A
constexpr float THR = 40.0f;                      // defer-max threshold (base-2)
constexpr float NEG_LOW  = -1.0e5f;
constexpr float NEG_MASK = -1.0e30f;

__device__ __forceinline__ float exp2fast(float x) { return __builtin_amdgcn_exp2f(x); }

// ---------------- prep: A -> f16 row-major (pre-scaled); B -> f16 k-major ----------------
// bT layout: [kq 0..15][col 0..8191][e 0..7]
__global__ void prep_kernel(const float* __restrict__ a, const float* __restrict__ b,
                            short* __restrict__ aH, short* __restrict__ bT)
{
    const int NPER = B_N * D_KK / 8;                  // 131072
    int i = blockIdx.x * blockDim.x + threadIdx.x;
    if (i < NPER) {
        const f32x4* sp = (const f32x4*)(a + (size_t)i * 8);
        f32x4 v0 = sp[0], v1 = sp[1];
        short8 h;
#pragma unroll
        for (int e = 0; e < 4; ++e) {
            h[e]     = __builtin_bit_cast(short, (_Float16)(C_SCALE * v0[e]));
            h[e + 4] = __builtin_bit_cast(short, (_Float16)(C_SCALE * v1[e]));
        }
        *(short8*)(aH + (size_t)i * 8) = h;
    } else {
        int j   = i - NPER;
        int kq  = j & 15;
        int col = j >> 4;
        const f32x4* sp = (const f32x4*)(b + (size_t)col * D_KK + kq * 8);
        f32x4 v0 = sp[0], v1 = sp[1];
        short8 h;
#pragma unroll
        for (int e = 0; e < 4; ++e) {
            h[e]     = __builtin_bit_cast(short, (_Float16)v0[e]);
            h[e + 4] = __builtin_bit_cast(short, (_Float16)v1[e]);
        }
        *(short8*)(bT + (size_t)kq * B_N * 8 + (size_t)col * 8) = h;
    }
}

// ---------------- main: LDS-free, barrier-free; frozen-ref epilogue; acc pre-biased ----------------
// 256 thr = 4 independent waves, each: 32 rows x 512 chunk cols.
// s[i] accumulates 2^(d - ref[i]); ref raised only when row max exceeds ref+THR.
// MFMA C-in initialized to -ref -> no per-value subtraction in the epilogue.
__global__ __launch_bounds__(256)
void rowstats_kernel(const short* __restrict__ aH, const short* __restrict__ bT,
                     const int* __restrict__ labels,
                     float* __restrict__ pmx, float* __restrict__ ps)
{
    const int bid   = blockIdx.x;
    const int chunk = bid & (NCHUNK - 1);          // bid&7 -> XCD affinity
    const int R0    = (bid >> 4) * 128;
    const int C0    = chunk * CCOLS;

    const int tid = threadIdx.x;
    const int wid = tid >> 6, l = tid & 63;
    const int l15 = l & 15, l16 = l >> 4;
    const int wrow = R0 + wid * 32;

    // A fragments -> registers (32 rows x 128 K, pre-scaled by C_SCALE)
    half8 aF[2][4];
#pragma unroll
    for (int mf = 0; mf < 2; ++mf) {
        const int arow = wrow + mf * 16 + l15;
#pragma unroll
        for (int ks = 0; ks < 4; ++ks)
            aF[mf][ks] = __builtin_bit_cast(half8,
                *(const short8*)(aH + (size_t)arow * D_KK + ks * 32 + l16 * 8));
    }

    int labA[8];
#pragma unroll
    for (int mf = 0; mf < 2; ++mf)
#pragma unroll
        for (int r = 0; r < 4; ++r)
            labA[mf * 4 + r] = labels[wrow + mf * 16 + l16 * 4 + r];

    float mxr[8], sm[8], ref[8];                   // mxr = masked max - ref (monotone)
#pragma unroll
    for (int i = 0; i < 8; ++i) { mxr[i] = NEG_LOW; sm[i] = 0.0f; ref[i] = 0.0f; }

    // B fragment offsets (bytes from cb), 32-bit: [nf][ks]
    const char* cb = (const char*)(bT + (size_t)C0 * 8);
    int vo[2][4];
#pragma unroll
    for (int nf = 0; nf < 2; ++nf)
#pragma unroll
        for (int ks = 0; ks < 4; ++ks)
            vo[nf][ks] = ((ks * 4 + l16) * B_N + nf * 16 + l15) * 16;

    const int NT = CCOLS / 32;                     // 16 tiles

    half8 bF[2][4];
#pragma unroll
    for (int nf = 0; nf < 2; ++nf)
#pragma unroll
        for (int ks = 0; ks < 4; ++ks)
            bF[nf][ks] = __builtin_bit_cast(half8, *(const short8*)(cb + vo[nf][ks]));

#pragma unroll 1
    for (int t = 0; t < NT; ++t) {
        // acc pre-biased: C-in = -ref[row]
        f32x4 acc[2][2];
#pragma unroll
        for (int mf = 0; mf < 2; ++mf)
#pragma unroll
            for (int nf = 0; nf < 2; ++nf)
#pragma unroll
                for (int r = 0; r < 4; ++r) acc[mf][nf][r] = -ref[mf * 4 + r];

#pragma unroll
        for (int ks = 0; ks < 4; ++ks)
#pragma unroll
            for (int mf = 0; mf < 2; ++mf)
#pragma unroll
                for (int nf = 0; nf < 2; ++nf)
                    acc[mf][nf] = __builtin_amdgcn_mfma_f32_16x16x32_f16(
                        aF[mf][ks], bF[nf][ks], acc[mf][nf], 0, 0, 0);

        // prefetch next tile's B fragments (bF dead after MFMA; latency hides under epilogue)
        if (t + 1 < NT) {
            const int off = (t + 1) * 512;         // 32 cols * 16B
#pragma unroll
            for (int nf = 0; nf < 2; ++nf)
#pragma unroll
                for (int ks = 0; ks < 4; ++ks)
                    bF[nf][ks] = __builtin_bit_cast(half8,
                        *(const short8*)(cb + vo[nf][ks] + off));
        }

        const int colB = C0 + t * 32;
        const int lB0 = labels[colB + l15];
        const int lB1 = labels[colB + 16 + l15];

        // ---- epilogue: masked, frozen-ref ----
        float vm0[8], vm1[8];
        int trig = 0;
#pragma unroll
        for (int mf = 0; mf < 2; ++mf)
#pragma unroll
            for (int r = 0; r < 4; ++r) {
                const int i = mf * 4 + r;
                float v0 = (lB0 != labA[i]) ? acc[mf][0][r] : NEG_MASK;
                float v1 = (lB1 != labA[i]) ? acc[mf][1][r] : NEG_MASK;
                mxr[i] = fmaxf(fmaxf(mxr[i], v0), v1);
                vm0[i] = v0; vm1[i] = v1;
                trig |= (mxr[i] > THR) ? 1 : 0;
            }
        if (__any(trig)) {                         // re-anchor (rare after early tiles)
#pragma unroll
            for (int i = 0; i < 8; ++i) {
                float dlt = fmaxf(mxr[i], 0.0f);
                sm[i] *= exp2fast(-dlt);           // dlt>=0; first anchor: 0*0=0 ok
                ref[i] += dlt; mxr[i] -= dlt;
                vm0[i] -= dlt; vm1[i] -= dlt;
            }
        }
#pragma unroll
        for (int i = 0; i < 8; ++i)
            sm[i] += exp2fast(vm0[i]) + exp2fast(vm1[i]);
    }

    // convert each lane's partial to (masked max, s rel masked max), then combine
    float mxa[8], so[8];
#pragma unroll
    for (int i = 0; i < 8; ++i) {
        mxa[i] = ref[i] + mxr[i];
        so[i]  = sm[i] * exp2fast(fminf(-mxr[i], 126.0f));   // clamp guards mxr=NEG_LOW
    }
#pragma unroll
    for (int i = 0; i < 8; ++i) {
#pragma unroll
        for (int off = 1; off < 16; off <<= 1) {
            float m2 = __shfl_xor(mxa[i], off);
            float s2 = __shfl_xor(so[i], off);
            float nm = fmaxf(mxa[i], m2);
            so[i] = so[i] * exp2fast(mxa[i] - nm) + s2 * exp2fast(m2 - nm);
            mxa[i] = nm;
        }
    }
    if (l15 == 0) {
#pragma unroll
        for (int mf = 0; mf < 2; ++mf)
#pragma unroll
            for (int r = 0; r < 4; ++r) {
                int row = wrow + mf * 16 + l16 * 4 + r;
                pmx[chunk * B_N + row] = mxa[mf * 4 + r];
                ps [chunk * B_N + row] = so[mf * 4 + r];
            }
    }
}

// ---------------- per-row chunk combine + per-block class partials ----------------
__global__ void classsum_kernel(const float* __restrict__ pmx, const float* __restrict__ ps,
                                const int* __restrict__ labels,
                                float* __restrict__ partSum, unsigned int* __restrict__ partCnt)
{
    __shared__ float        csL[NCLS];
    __shared__ unsigned int ccL[NCLS];
    int t = threadIdx.x;
    if (t < NCLS) { csL[t] = 0.0f; ccL[t] = 0u; }
    __syncthreads();

    int j = blockIdx.x * blockDim.x + t;
    float m = -FLT_MAX, s = 0.0f;
#pragma unroll 4
    for (int c = 0; c < NCHUNK; ++c) {
        float m2 = pmx[(size_t)c * B_N + j];
        float s2 = ps [(size_t)c * B_N + j];
        float nm = fmaxf(m, m2);
        s = s * exp2fast(m - nm) + s2 * exp2fast(m2 - nm);
        m = nm;
    }
    int lab = labels[j];
    atomicAdd(&csL[lab], s);
    atomicAdd(&ccL[lab], 1u);
    __syncthreads();
    if (t < NCLS) {
        partSum[blockIdx.x * NCLS + t] = csL[t];
        partCnt[blockIdx.x * NCLS + t] = ccL[t];
    }
}

__global__ void loss_kernel(const float* __restrict__ partSum,
                            const unsigned int* __restrict__ partCnt,
                            float* __restrict__ out)
{
    int c = threadIdx.x;  // 64 threads = 1 wave
    float cs = 0.0f;
    unsigned int cc = 0u;
    if (c < NCLS) {
#pragma unroll 4
        for (int b = 0; b < NPBLK; ++b) {
            cs += partSum[b * NCLS + c];
            cc += partCnt[b * NCLS + c];
        }
    }

    float tot = cs;
#pragma unroll
    for (int off = 1; off < 64; off <<= 1) tot += __shfl_xor(tot, off);

    float contrib = 0.0f;
    if (c < NCLS && cc > 0u) {
        float negc = (float)(B_N - (int)cc);
        float nds  = tot - cs;
        float x    = (negc > 0.0f) ? (nds / negc) : nds;
        float lp   = (cc >= 2u) ? (-logf(x + 1e-12f)) : 0.0f;
        contrib = (float)cc * lp;
    }
#pragma unroll
    for (int off = 1; off < 64; off <<= 1) contrib += __shfl_xor(contrib, off);
    if (c == 0) out[0] = -(contrib / (float)B_N);
}

extern "C" void kernel_launch(void* const* d_in, const int* in_sizes, int n_in,
                              void* d_out, int out_size, void* d_ws, size_t ws_size,
                              hipStream_t stream)
{
    const float* anchor = (const float*)d_in[0];
    const float* target = (const float*)d_in[1];
    const int*   labels = (const int*)d_in[2];
    float* out = (float*)d_out;

    const size_t PLANE = (size_t)B_N * D_KK * sizeof(short);   // 2 MB
    char* ws = (char*)d_ws;
    short* aH = (short*)(ws + 0 * PLANE);
    short* bT = (short*)(ws + 1 * PLANE);
    float* ps  = (float*)(ws + 2 * PLANE);
    float* pmx = (float*)(ws + 2 * PLANE + sizeof(float) * NCHUNK * B_N);
    char*  cls = ws + 2 * PLANE + 2 * sizeof(float) * NCHUNK * B_N;
    float*        partSum = (float*)cls;
    unsigned int* partCnt = (unsigned int*)(cls + NPBLK * NCLS * sizeof(float));

    prep_kernel<<<2 * (B_N * D_KK / 8) / 256, 256, 0, stream>>>(anchor, target, aH, bT);
    rowstats_kernel<<<(B_N / 128) * NCHUNK, 256, 0, stream>>>(aH, bT, labels, pmx, ps);
    classsum_kernel<<<B_N / 256, 256, 0, stream>>>(pmx, ps, labels, partSum, partCnt);
    loss_kernel<<<1, 64, 0, stream>>>(partSum, partCnt, out);
}